// Round 5
// baseline (431.534 us; speedup 1.0000x reference)
//
#include <hip/hip_runtime.h>
#include <hip/hip_bf16.h>
#include <math.h>

#define MDIM 8192
#define NDIM 4096
#define KDIM 4096
#define WELEMS 16777216
#define XELEMS 33554432

typedef __attribute__((ext_vector_type(8))) short bf16x8;
typedef __attribute__((ext_vector_type(4))) float f32x4;

__device__ __forceinline__ unsigned short f2bf(float f) {
  unsigned int u = __float_as_uint(f);
  u += 0x7fffu + ((u >> 16) & 1u);   // RNE
  return (unsigned short)(u >> 16);
}

__device__ __forceinline__ void gload16(const void* g, void* l) {
  __builtin_amdgcn_global_load_lds(
      (const __attribute__((address_space(1))) void*)g,
      (__attribute__((address_space(3))) void*)l, 16, 0, 0);
}

// ===== numpy-exact fp32 pairwise summation (verified round 3/4) =====
template <int MODE>   // 0: sum w ; 1: sum (w-mean)^2 ; 2: sum |w|*keep & count
__global__ __launch_bounds__(256)
void np_stage1(const float* __restrict__ w, float* __restrict__ C,
               float* __restrict__ C2, const float* __restrict__ scal) {
  __shared__ float ls[32], ls2[32];
  const int t = threadIdx.x;
  const int leaf = t >> 3, j = t & 7;
  const size_t base = (size_t)blockIdx.x * 4096 + leaf * 128 + j;
  float mean = 0.f, lower = 0.f, upper = 0.f;
  if (MODE == 1) mean = scal[0];
  if (MODE == 2) { lower = scal[1]; upper = scal[2]; }
  float r = 0.f, r2 = 0.f;
#pragma unroll
  for (int s = 0; s < 16; s++) {
    float v = w[base + s * 8];
    float tv, tv2 = 0.f;
    if (MODE == 0) tv = v;
    else if (MODE == 1) { float x = v - mean; tv = __fmul_rn(x, x); }
    else {
      bool keep = !(v < lower || v > upper);
      tv = keep ? fabsf(v) : 0.f;
      tv2 = keep ? 1.f : 0.f;
    }
    if (s == 0) { r = tv; r2 = tv2; } else { r += tv; r2 += tv2; }
  }
  r += __shfl_xor(r, 1); r += __shfl_xor(r, 2); r += __shfl_xor(r, 4);
  if (MODE == 2) { r2 += __shfl_xor(r2, 1); r2 += __shfl_xor(r2, 2); r2 += __shfl_xor(r2, 4); }
  if (j == 0) { ls[leaf] = r; if (MODE == 2) ls2[leaf] = r2; }
  __syncthreads();
  if (t == 0) {
    float tmp[32];
    for (int i = 0; i < 32; i++) tmp[i] = ls[i];
    for (int n = 32; n > 1; n >>= 1)
      for (int i = 0; i < n / 2; i++) tmp[i] = tmp[2 * i] + tmp[2 * i + 1];
    C[blockIdx.x] = tmp[0];
    if (MODE == 2) {
      for (int i = 0; i < 32; i++) tmp[i] = ls2[i];
      for (int n = 32; n > 1; n >>= 1)
        for (int i = 0; i < n / 2; i++) tmp[i] = tmp[2 * i] + tmp[2 * i + 1];
      C2[blockIdx.x] = tmp[0];
    }
  }
}

template <int MODE>
__global__ __launch_bounds__(256)
void np_stage2(const float* __restrict__ C, const float* __restrict__ C2,
               float* __restrict__ scal) {
  __shared__ float ls[256], ls2[256];
  const int t = threadIdx.x;
  {
    float v[16];
    for (int i = 0; i < 16; i++) v[i] = C[t * 16 + i];
    for (int n = 16; n > 1; n >>= 1)
      for (int i = 0; i < n / 2; i++) v[i] = v[2 * i] + v[2 * i + 1];
    ls[t] = v[0];
    if (MODE == 2) {
      for (int i = 0; i < 16; i++) v[i] = C2[t * 16 + i];
      for (int n = 16; n > 1; n >>= 1)
        for (int i = 0; i < n / 2; i++) v[i] = v[2 * i] + v[2 * i + 1];
      ls2[t] = v[0];
    }
  }
  __syncthreads();
  if (t == 0) {
    float tmp[256];
    for (int i = 0; i < 256; i++) tmp[i] = ls[i];
    for (int n = 256; n > 1; n >>= 1)
      for (int i = 0; i < n / 2; i++) tmp[i] = tmp[2 * i] + tmp[2 * i + 1];
    float S = tmp[0];
    if (MODE == 0) {
      scal[0] = S / 16777216.0f;
    } else if (MODE == 1) {
      float var = S / 16777215.0f;
      float sd = sqrtf(var);
      float mean = scal[0];
      scal[1] = mean - __fmul_rn(1.96f, sd);
      scal[2] = mean + __fmul_rn(1.96f, sd);
    } else {
      for (int i = 0; i < 256; i++) tmp[i] = ls2[i];
      for (int n = 256; n > 1; n >>= 1)
        for (int i = 0; i < n / 2; i++) tmp[i] = tmp[2 * i] + tmp[2 * i + 1];
      scal[3] = S / tmp[0];
    }
  }
}

// ===== converts =====
__device__ __forceinline__ void pack8(const float* __restrict__ p, unsigned short* dst,
                                      bool dobin, float lower, float upper, float scale) {
  float4 u = *(const float4*)p;
  float4 v = *(const float4*)(p + 4);
  float f[8] = {u.x, u.y, u.z, u.w, v.x, v.y, v.z, v.w};
  unsigned int r[4];
#pragma unroll
  for (int j = 0; j < 4; j++) {
    float a = f[2 * j], b = f[2 * j + 1];
    if (dobin) {
      bool oa = (a < lower) || (a > upper);
      bool ob = (b < lower) || (b > upper);
      a = oa ? a : __fmul_rn(a, scale);
      b = ob ? b : __fmul_rn(b, scale);
    }
    r[j] = (unsigned int)f2bf(a) | ((unsigned int)f2bf(b) << 16);
  }
  *(uint4*)dst = make_uint4(r[0], r[1], r[2], r[3]);
}

__global__ __launch_bounds__(256)
void convert_w(const float* __restrict__ w, unsigned short* __restrict__ wb,
               const float* __restrict__ scal) {
  float lower = scal[1], upper = scal[2], scale = scal[3];
  int tid = blockIdx.x * blockDim.x + threadIdx.x;
  int nth = gridDim.x * blockDim.x;
  int nc = WELEMS / 8;
  for (int i = tid; i < nc; i += nth)
    pack8(w + (size_t)i * 8, wb + (size_t)i * 8, true, lower, upper, scale);
}

__global__ __launch_bounds__(256)
void convert_x(const float* __restrict__ x, unsigned short* __restrict__ xb) {
  int tid = blockIdx.x * blockDim.x + threadIdx.x;
  int nth = gridDim.x * blockDim.x;
  int nc = XELEMS / 8;
  for (int i = tid; i < nc; i += nth)
    pack8(x + (size_t)i * 8, xb + (size_t)i * 8, false, 0.f, 0.f, 0.f);
}

// ===== 256x256 8-phase bf16 MFMA GEMM (T2+T3+T4+T5, m201 phase order) =====
// 512 thr = 8 waves (2M x 4N); BK=64; LDS 128KB. Per phase (m201):
//   {ds_read this phase's frags} {stage 2x gload_lds} [VM at ph4/ph8]
//   -> BARRIER -> setprio(1) 16 MFMA setprio(0) -> BARRIER
// ds_read latency hides under barrier convergence; vmcnt counted (2),
// never 0 in-loop; stationary outstanding 10 -> drains to 2 at ph4/ph8.
// MFMA order ks-outer: 8 independent MFMAs between dependent acc pairs.

#define VM2  asm volatile("s_waitcnt vmcnt(2)" ::: "memory")
#define VM0  asm volatile("s_waitcnt vmcnt(0)" ::: "memory")
#define LGK8 asm volatile("s_waitcnt lgkmcnt(8)" ::: "memory")
#define PSYNC { asm volatile("" ::: "memory"); __builtin_amdgcn_s_barrier(); asm volatile("" ::: "memory"); }

#define LDA(buf, mh) { \
  a[0][0] = *(const bf16x8*)&sA[buf][wm][((mh)*64 +  0 + fr)*64 + koo0]; \
  a[0][1] = *(const bf16x8*)&sA[buf][wm][((mh)*64 +  0 + fr)*64 + koo1]; \
  a[1][0] = *(const bf16x8*)&sA[buf][wm][((mh)*64 + 16 + fr)*64 + koo0]; \
  a[1][1] = *(const bf16x8*)&sA[buf][wm][((mh)*64 + 16 + fr)*64 + koo1]; \
  a[2][0] = *(const bf16x8*)&sA[buf][wm][((mh)*64 + 32 + fr)*64 + koo0]; \
  a[2][1] = *(const bf16x8*)&sA[buf][wm][((mh)*64 + 32 + fr)*64 + koo1]; \
  a[3][0] = *(const bf16x8*)&sA[buf][wm][((mh)*64 + 48 + fr)*64 + koo0]; \
  a[3][1] = *(const bf16x8*)&sA[buf][wm][((mh)*64 + 48 + fr)*64 + koo1]; }

#define LDB(buf, nh) { \
  b[0][0] = *(const bf16x8*)&sB[buf][wnh][(wnq*64 + (nh)*32 +  0 + fr)*64 + koo0]; \
  b[0][1] = *(const bf16x8*)&sB[buf][wnh][(wnq*64 + (nh)*32 +  0 + fr)*64 + koo1]; \
  b[1][0] = *(const bf16x8*)&sB[buf][wnh][(wnq*64 + (nh)*32 + 16 + fr)*64 + koo0]; \
  b[1][1] = *(const bf16x8*)&sB[buf][wnh][(wnq*64 + (nh)*32 + 16 + fr)*64 + koo1]; }

#define MM1(m, n, ks) acc[m][n] = __builtin_amdgcn_mfma_f32_16x16x32_bf16(a[(m)&3][ks], b[(n)&1][ks], acc[m][n], 0, 0, 0)
#define MMKS(mh, nh, ks) { \
  MM1((mh)*4+0, (nh)*2+0, ks); MM1((mh)*4+0, (nh)*2+1, ks); \
  MM1((mh)*4+1, (nh)*2+0, ks); MM1((mh)*4+1, (nh)*2+1, ks); \
  MM1((mh)*4+2, (nh)*2+0, ks); MM1((mh)*4+2, (nh)*2+1, ks); \
  MM1((mh)*4+3, (nh)*2+0, ks); MM1((mh)*4+3, (nh)*2+1, ks); }
#define MM(mh, nh) { \
  __builtin_amdgcn_s_setprio(1); \
  MMKS(mh, nh, 0); MMKS(mh, nh, 1); \
  __builtin_amdgcn_s_setprio(0); }

#define STGA(buf, q, ku) { \
  gload16(xbp + aoff[0][q] + (ku), &sA[buf][0][(q)*4096 + t8]); \
  gload16(xbp + aoff[1][q] + (ku), &sA[buf][1][(q)*4096 + t8]); }
#define STGB(buf, h, ku) { \
  gload16(wbp + boff[h][0] + (ku), &sB[buf][h][t8]); \
  gload16(wbp + boff[h][1] + (ku), &sB[buf][h][4096 + t8]); }

__global__ __launch_bounds__(512, 2)
void gemm256(const unsigned short* __restrict__ xbp, const unsigned short* __restrict__ wbp,
             const float* __restrict__ bias, float* __restrict__ out) {
  __shared__ unsigned short sA[2][2][8192];
  __shared__ unsigned short sB[2][2][8192];

  // XCD-aware bijective swizzle: grid 512 = 32(M) x 16(N), 512 % 8 == 0
  const int bid = blockIdx.x;
  const int swz = (bid & 7) * 64 + (bid >> 3);
  const int bm = swz >> 4;
  const int bn = swz & 15;

  const int t = threadIdx.x;
  const int lane = t & 63;
  const int wid = t >> 6;
  const int wm = wid >> 2;        // 0..1 (M half)
  const int wn = wid & 3;         // 0..3
  const int wnh = wn >> 1;        // B half
  const int wnq = wn & 1;         // quarter within B half
  const int fr = lane & 15;
  const int ko = (lane >> 4) * 8;
  const int xr = (fr & 7) << 3;   // read-side XOR swizzle
  const int koo0 = ko ^ xr;
  const int koo1 = (32 + ko) ^ xr;

  const int t8 = t * 8;
  const int rl = t >> 3;                          // local row 0..63 (per q)
  const int cs = ((t & 7) * 8) ^ ((rl & 7) << 3); // inverse-swizzled src col
  size_t aoff[2][2], boff[2][2];
#pragma unroll
  for (int h = 0; h < 2; h++)
#pragma unroll
    for (int q = 0; q < 2; q++) {
      aoff[h][q] = (size_t)(bm * 256 + h * 128 + q * 64 + rl) * KDIM + cs;
      boff[h][q] = (size_t)(bn * 256 + h * 128 + q * 64 + rl) * KDIM + cs;
    }

  f32x4 acc[8][4];
#pragma unroll
  for (int i = 0; i < 8; i++)
#pragma unroll
    for (int j = 0; j < 4; j++) acc[i][j] = {0.f, 0.f, 0.f, 0.f};

  bf16x8 a[4][2], b[2][2];

  // prologue: buf0 (8 loads) + buf1 q0 A (2) = 10 outstanding
  STGA(0, 0, 0); STGA(0, 1, 0); STGB(0, 0, 0); STGB(0, 1, 0);
  STGA(1, 0, 64);
  VM2; PSYNC;                      // buf0 confirmed

  const int NIT = KDIM / 128;      // 32 iterations, 2 K-tiles each
  for (int it = 0; it < NIT; ++it) {
    const bool last = (it == NIT - 1);
    const int kuB = it * 128 + 64;   // K-tile 2it+1 (buf1)
    const int kuN = kuB + 64;        // K-tile 2it+2 (buf0 next)

    // ---- K-tile A (buf0): quadrants (0,0),(0,1),(1,1),(1,0) ----
    LDA(0, 0); LDB(0, 0);
    STGA(1, 1, kuB);
    LGK8; PSYNC;
    MM(0, 0); PSYNC;

    LDB(0, 1);
    STGB(1, 0, kuB);
    PSYNC;
    MM(0, 1); PSYNC;

    LDA(0, 1);
    STGB(1, 1, kuB);
    PSYNC;
    MM(1, 1); PSYNC;

    LDB(0, 0);
    if (!last) STGA(0, 0, kuN);
    if (last) { VM0; } else { VM2; }   // confirm buf1's 8 loads
    PSYNC;
    MM(1, 0); PSYNC;

    // ---- K-tile B (buf1) ----
    LDA(1, 0); LDB(1, 0);
    if (!last) STGA(0, 1, kuN);
    LGK8; PSYNC;
    MM(0, 0); PSYNC;

    LDB(1, 1);
    if (!last) STGB(0, 0, kuN);
    PSYNC;
    MM(0, 1); PSYNC;

    LDA(1, 1);
    if (!last) STGB(0, 1, kuN);
    PSYNC;
    MM(1, 1); PSYNC;

    LDB(1, 0);
    if (!last) {
      STGA(1, 0, kuN + 64);            // next iteration's buf1 q0 A
      VM2;                             // confirm buf0-next's 8 loads
    }
    PSYNC;
    MM(1, 0); PSYNC;
  }

  // epilogue: C/D layout col = lane&15, row = (lane>>4)*4 + q
#pragma unroll
  for (int nn = 0; nn < 4; ++nn) {
    const int col = bn * 256 + wn * 64 + nn * 16 + (lane & 15);
    const float bv = bias[col];
#pragma unroll
    for (int m = 0; m < 8; ++m) {
      const int row0 = bm * 256 + wm * 128 + m * 16 + (lane >> 4) * 4;
#pragma unroll
      for (int q = 0; q < 4; ++q)
        out[(size_t)(row0 + q) * NDIM + col] = acc[m][nn][q] + bv;
    }
  }
}

// ===== fallback 128^2 GEMM (round-3 verified) for small-ws paths =====
template <bool A_BF16, bool B_BF16>
__global__ __launch_bounds__(256)
void gemm_bt(const void* __restrict__ Av, const void* __restrict__ Bv,
             const float* __restrict__ bias, float* __restrict__ out,
             const float* __restrict__ scal) {
  __shared__ unsigned short sAt[2][128 * 32];
  __shared__ unsigned short sBt[2][128 * 32];
  float lower = 0.f, upper = 0.f, scale = 0.f;
  if constexpr (!B_BF16) { lower = scal[1]; upper = scal[2]; scale = scal[3]; }
  const unsigned short* Ab = (const unsigned short*)Av;
  const float* Af = (const float*)Av;
  const unsigned short* Bb = (const unsigned short*)Bv;
  const float* Bf = (const float*)Bv;
  int bid = blockIdx.x;
  int swz = (bid & 7) * 256 + (bid >> 3);
  int bm = swz >> 5, bn = swz & 31;
  const int t = threadIdx.x, lane = t & 63, wid = t >> 6;
  const int wm = wid >> 1, wn = wid & 1;
  const int e0 = t * 8, e1 = e0 + 2048;
  const size_t aOff0 = (size_t)(bm * 128 + (e0 >> 5)) * KDIM + (e0 & 31);
  const size_t aOff1 = (size_t)(bm * 128 + (e1 >> 5)) * KDIM + (e1 & 31);
  const size_t bOff0 = (size_t)(bn * 128 + (e0 >> 5)) * KDIM + (e0 & 31);
  const size_t bOff1 = (size_t)(bn * 128 + (e1 >> 5)) * KDIM + (e1 & 31);
  f32x4 acc[4][4];
#pragma unroll
  for (int i = 0; i < 4; i++)
#pragma unroll
    for (int j = 0; j < 4; j++) acc[i][j] = {0.f, 0.f, 0.f, 0.f};
  auto stage = [&](int buf, int k0) {
    if constexpr (A_BF16) {
      gload16(Ab + aOff0 + k0, &sAt[buf][e0]);
      gload16(Ab + aOff1 + k0, &sAt[buf][e1]);
    } else {
      pack8(Af + aOff0 + k0, &sAt[buf][e0], false, 0.f, 0.f, 0.f);
      pack8(Af + aOff1 + k0, &sAt[buf][e1], false, 0.f, 0.f, 0.f);
    }
    if constexpr (B_BF16) {
      gload16(Bb + bOff0 + k0, &sBt[buf][e0]);
      gload16(Bb + bOff1 + k0, &sBt[buf][e1]);
    } else {
      pack8(Bf + bOff0 + k0, &sBt[buf][e0], true, lower, upper, scale);
      pack8(Bf + bOff1 + k0, &sBt[buf][e1], true, lower, upper, scale);
    }
  };
  stage(0, 0);
  const int NT = KDIM / 32;
  const int ko = (lane >> 4) * 8, fr = lane & 15;
  for (int tt = 0; tt < NT; ++tt) {
    int cur = tt & 1;
    __syncthreads();
    if (tt + 1 < NT) stage(cur ^ 1, (tt + 1) * 32);
    bf16x8 a[4], b[4];
#pragma unroll
    for (int i = 0; i < 4; i++) {
      a[i] = *(const bf16x8*)&sAt[cur][(wm * 64 + i * 16 + fr) * 32 + ko];
      b[i] = *(const bf16x8*)&sBt[cur][(wn * 64 + i * 16 + fr) * 32 + ko];
    }
#pragma unroll
    for (int i = 0; i < 4; i++)
#pragma unroll
      for (int j = 0; j < 4; j++)
        acc[i][j] = __builtin_amdgcn_mfma_f32_16x16x32_bf16(a[i], b[j], acc[i][j], 0, 0, 0);
  }
  const int colbase = bn * 128 + wn * 64 + (lane & 15);
  const int rowbase = bm * 128 + wm * 64 + (lane >> 4) * 4;
#pragma unroll
  for (int j = 0; j < 4; j++) {
    int col = colbase + j * 16;
    float bv = bias[col];
#pragma unroll
    for (int i = 0; i < 4; i++) {
      int row0 = rowbase + i * 16;
#pragma unroll
      for (int q = 0; q < 4; q++)
        out[(size_t)(row0 + q) * NDIM + col] = acc[i][j][q] + bv;
    }
  }
}

extern "C" void kernel_launch(void* const* d_in, const int* in_sizes, int n_in,
                              void* d_out, int out_size, void* d_ws, size_t ws_size,
                              hipStream_t stream) {
  const float* x = (const float*)d_in[0];
  const float* w = (const float*)d_in[1];
  const float* bias = (const float*)d_in[2];
  float* out = (float*)d_out;
  char* ws = (char*)d_ws;

  const size_t xb_b = (size_t)XELEMS * 2;   // 64 MB
  const size_t wb_b = (size_t)WELEMS * 2;   // 32 MB
  const size_t c_b = 4 * 4096 * sizeof(float);
  const bool full = ws_size >= xb_b + wb_b + c_b + 64;
  const bool wonly = !full && ws_size >= wb_b + c_b + 64;

  unsigned short *xb = nullptr, *wb = nullptr;
  float *C1, *scal;
  if (full) {
    xb = (unsigned short*)ws;
    wb = (unsigned short*)(ws + xb_b);
    C1 = (float*)(ws + xb_b + wb_b);
  } else if (wonly) {
    wb = (unsigned short*)ws;
    C1 = (float*)(ws + wb_b);
  } else {
    C1 = (float*)ws;
  }
  float* C2 = C1 + 4096;
  float* C3 = C2 + 4096;
  float* C4 = C3 + 4096;
  scal = C4 + 4096;

  np_stage1<0><<<dim3(4096), dim3(256), 0, stream>>>(w, C1, nullptr, scal);
  np_stage2<0><<<dim3(1), dim3(256), 0, stream>>>(C1, nullptr, scal);
  np_stage1<1><<<dim3(4096), dim3(256), 0, stream>>>(w, C2, nullptr, scal);
  np_stage2<1><<<dim3(1), dim3(256), 0, stream>>>(C2, nullptr, scal);
  np_stage1<2><<<dim3(4096), dim3(256), 0, stream>>>(w, C3, C4, scal);
  np_stage2<2><<<dim3(1), dim3(256), 0, stream>>>(C3, C4, scal);

  if (full) {
    convert_w<<<dim3(2048), dim3(256), 0, stream>>>(w, wb, scal);
    convert_x<<<dim3(4096), dim3(256), 0, stream>>>(x, xb);
    gemm256<<<dim3(512), dim3(512), 0, stream>>>(xb, wb, bias, out);
  } else if (wonly) {
    convert_w<<<dim3(2048), dim3(256), 0, stream>>>(w, wb, scal);
    gemm_bt<false, true><<<dim3(2048), dim3(256), 0, stream>>>(x, wb, bias, out, scal);
  } else {
    gemm_bt<false, false><<<dim3(2048), dim3(256), 0, stream>>>(x, w, bias, out, scal);
  }
}

// Round 6
// 414.328 us; speedup vs baseline: 1.0415x; 1.0415x over previous
//
#include <hip/hip_runtime.h>
#include <hip/hip_bf16.h>
#include <math.h>

#define MDIM 8192
#define NDIM 4096
#define KDIM 4096
#define WELEMS 16777216
#define XELEMS 33554432

typedef __attribute__((ext_vector_type(8))) short bf16x8;
typedef __attribute__((ext_vector_type(4))) float f32x4;

__device__ __forceinline__ unsigned short f2bf(float f) {
  unsigned int u = __float_as_uint(f);
  u += 0x7fffu + ((u >> 16) & 1u);   // RNE
  return (unsigned short)(u >> 16);
}

__device__ __forceinline__ void gload16(const void* g, void* l) {
  __builtin_amdgcn_global_load_lds(
      (const __attribute__((address_space(1))) void*)g,
      (__attribute__((address_space(3))) void*)l, 16, 0, 0);
}

// ===== numpy-exact fp32 pairwise summation (verified rounds 3-5) =====
template <int MODE>   // 0: sum w ; 1: sum (w-mean)^2 ; 2: sum |w|*keep & count
__global__ __launch_bounds__(256)
void np_stage1(const float* __restrict__ w, float* __restrict__ C,
               float* __restrict__ C2, const float* __restrict__ scal) {
  __shared__ float ls[32], ls2[32];
  const int t = threadIdx.x;
  const int leaf = t >> 3, j = t & 7;
  const size_t base = (size_t)blockIdx.x * 4096 + leaf * 128 + j;
  float mean = 0.f, lower = 0.f, upper = 0.f;
  if (MODE == 1) mean = scal[0];
  if (MODE == 2) { lower = scal[1]; upper = scal[2]; }
  float r = 0.f, r2 = 0.f;
#pragma unroll
  for (int s = 0; s < 16; s++) {
    float v = w[base + s * 8];
    float tv, tv2 = 0.f;
    if (MODE == 0) tv = v;
    else if (MODE == 1) { float x = v - mean; tv = __fmul_rn(x, x); }
    else {
      bool keep = !(v < lower || v > upper);
      tv = keep ? fabsf(v) : 0.f;
      tv2 = keep ? 1.f : 0.f;
    }
    if (s == 0) { r = tv; r2 = tv2; } else { r += tv; r2 += tv2; }
  }
  r += __shfl_xor(r, 1); r += __shfl_xor(r, 2); r += __shfl_xor(r, 4);
  if (MODE == 2) { r2 += __shfl_xor(r2, 1); r2 += __shfl_xor(r2, 2); r2 += __shfl_xor(r2, 4); }
  if (j == 0) { ls[leaf] = r; if (MODE == 2) ls2[leaf] = r2; }
  __syncthreads();
  if (t == 0) {
    float tmp[32];
    for (int i = 0; i < 32; i++) tmp[i] = ls[i];
    for (int n = 32; n > 1; n >>= 1)
      for (int i = 0; i < n / 2; i++) tmp[i] = tmp[2 * i] + tmp[2 * i + 1];
    C[blockIdx.x] = tmp[0];
    if (MODE == 2) {
      for (int i = 0; i < 32; i++) tmp[i] = ls2[i];
      for (int n = 32; n > 1; n >>= 1)
        for (int i = 0; i < n / 2; i++) tmp[i] = tmp[2 * i] + tmp[2 * i + 1];
      C2[blockIdx.x] = tmp[0];
    }
  }
}

template <int MODE>
__global__ __launch_bounds__(256)
void np_stage2(const float* __restrict__ C, const float* __restrict__ C2,
               float* __restrict__ scal) {
  __shared__ float ls[256], ls2[256];
  const int t = threadIdx.x;
  {
    float v[16];
    for (int i = 0; i < 16; i++) v[i] = C[t * 16 + i];
    for (int n = 16; n > 1; n >>= 1)
      for (int i = 0; i < n / 2; i++) v[i] = v[2 * i] + v[2 * i + 1];
    ls[t] = v[0];
    if (MODE == 2) {
      for (int i = 0; i < 16; i++) v[i] = C2[t * 16 + i];
      for (int n = 16; n > 1; n >>= 1)
        for (int i = 0; i < n / 2; i++) v[i] = v[2 * i] + v[2 * i + 1];
      ls2[t] = v[0];
    }
  }
  __syncthreads();
  if (t == 0) {
    float tmp[256];
    for (int i = 0; i < 256; i++) tmp[i] = ls[i];
    for (int n = 256; n > 1; n >>= 1)
      for (int i = 0; i < n / 2; i++) tmp[i] = tmp[2 * i] + tmp[2 * i + 1];
    float S = tmp[0];
    if (MODE == 0) {
      scal[0] = S / 16777216.0f;
    } else if (MODE == 1) {
      float var = S / 16777215.0f;
      float sd = sqrtf(var);
      float mean = scal[0];
      scal[1] = mean - __fmul_rn(1.96f, sd);
      scal[2] = mean + __fmul_rn(1.96f, sd);
    } else {
      for (int i = 0; i < 256; i++) tmp[i] = ls2[i];
      for (int n = 256; n > 1; n >>= 1)
        for (int i = 0; i < n / 2; i++) tmp[i] = tmp[2 * i] + tmp[2 * i + 1];
      scal[3] = S / tmp[0];
    }
  }
}

// ===== converts =====
__device__ __forceinline__ void pack8(const float* __restrict__ p, unsigned short* dst,
                                      bool dobin, float lower, float upper, float scale) {
  float4 u = *(const float4*)p;
  float4 v = *(const float4*)(p + 4);
  float f[8] = {u.x, u.y, u.z, u.w, v.x, v.y, v.z, v.w};
  unsigned int r[4];
#pragma unroll
  for (int j = 0; j < 4; j++) {
    float a = f[2 * j], b = f[2 * j + 1];
    if (dobin) {
      bool oa = (a < lower) || (a > upper);
      bool ob = (b < lower) || (b > upper);
      a = oa ? a : __fmul_rn(a, scale);
      b = ob ? b : __fmul_rn(b, scale);
    }
    r[j] = (unsigned int)f2bf(a) | ((unsigned int)f2bf(b) << 16);
  }
  *(uint4*)dst = make_uint4(r[0], r[1], r[2], r[3]);
}

__global__ __launch_bounds__(256)
void convert_w(const float* __restrict__ w, unsigned short* __restrict__ wb,
               const float* __restrict__ scal) {
  float lower = scal[1], upper = scal[2], scale = scal[3];
  int tid = blockIdx.x * blockDim.x + threadIdx.x;
  int nth = gridDim.x * blockDim.x;
  int nc = WELEMS / 8;
  for (int i = tid; i < nc; i += nth)
    pack8(w + (size_t)i * 8, wb + (size_t)i * 8, true, lower, upper, scale);
}

__global__ __launch_bounds__(256)
void convert_x(const float* __restrict__ x, unsigned short* __restrict__ xb) {
  int tid = blockIdx.x * blockDim.x + threadIdx.x;
  int nth = gridDim.x * blockDim.x;
  int nc = XELEMS / 8;
  for (int i = tid; i < nc; i += nth)
    pack8(x + (size_t)i * 8, xb + (size_t)i * 8, false, 0.f, 0.f, 0.f);
}

// ===== 256x256 8-phase bf16 MFMA GEMM (T2+T3+T4+T5, staggered vmcnt(6)) =====
// 512 thr = 8 waves (2M x 4N); BK=64; LDS 128KB (1 block/CU, LDS-bound).
// All 8 B-frags kept in regs (b0,b1) -> 24 ds_read_b128 per K-tile (no re-read).
// Stage schedule (2 loads/unit): ph1:T1.A1  ph3:T0'.B0+B1  ph4:T0'.A0+VM6
// ph5:T0'.A1  ph7:T1'.B0+B1  ph8:T1'.A0+VM6. Every load confirmed >=3 phases
// (~1300cyc > 900cyc HBM) after issue; invariant 6 outstanding at iter start;
// each VM6 confirms exactly one full K-tile. WAR: every region staged >=1
// end-barrier after its last reader's phase.

#define VM6  asm volatile("s_waitcnt vmcnt(6)" ::: "memory")
#define VM0  asm volatile("s_waitcnt vmcnt(0)" ::: "memory")
#define LGK8 asm volatile("s_waitcnt lgkmcnt(8)" ::: "memory")
#define PSYNC { asm volatile("" ::: "memory"); __builtin_amdgcn_s_barrier(); asm volatile("" ::: "memory"); }

#define LDA(buf, mh) { \
  a[0][0] = *(const bf16x8*)&sA[buf][wm][((mh)*64 +  0 + fr)*64 + koo0]; \
  a[0][1] = *(const bf16x8*)&sA[buf][wm][((mh)*64 +  0 + fr)*64 + koo1]; \
  a[1][0] = *(const bf16x8*)&sA[buf][wm][((mh)*64 + 16 + fr)*64 + koo0]; \
  a[1][1] = *(const bf16x8*)&sA[buf][wm][((mh)*64 + 16 + fr)*64 + koo1]; \
  a[2][0] = *(const bf16x8*)&sA[buf][wm][((mh)*64 + 32 + fr)*64 + koo0]; \
  a[2][1] = *(const bf16x8*)&sA[buf][wm][((mh)*64 + 32 + fr)*64 + koo1]; \
  a[3][0] = *(const bf16x8*)&sA[buf][wm][((mh)*64 + 48 + fr)*64 + koo0]; \
  a[3][1] = *(const bf16x8*)&sA[buf][wm][((mh)*64 + 48 + fr)*64 + koo1]; }

#define LDBX(buf, nh, bb) { \
  bb[0][0] = *(const bf16x8*)&sB[buf][wnh][(wnq*64 + (nh)*32 +  0 + fr)*64 + koo0]; \
  bb[0][1] = *(const bf16x8*)&sB[buf][wnh][(wnq*64 + (nh)*32 +  0 + fr)*64 + koo1]; \
  bb[1][0] = *(const bf16x8*)&sB[buf][wnh][(wnq*64 + (nh)*32 + 16 + fr)*64 + koo0]; \
  bb[1][1] = *(const bf16x8*)&sB[buf][wnh][(wnq*64 + (nh)*32 + 16 + fr)*64 + koo1]; }

#define MM1(m, n, ks, bb) acc[m][n] = __builtin_amdgcn_mfma_f32_16x16x32_bf16(a[(m)&3][ks], bb[(n)&1][ks], acc[m][n], 0, 0, 0)
#define MMKS(mh, nh, ks, bb) { \
  MM1((mh)*4+0, (nh)*2+0, ks, bb); MM1((mh)*4+0, (nh)*2+1, ks, bb); \
  MM1((mh)*4+1, (nh)*2+0, ks, bb); MM1((mh)*4+1, (nh)*2+1, ks, bb); \
  MM1((mh)*4+2, (nh)*2+0, ks, bb); MM1((mh)*4+2, (nh)*2+1, ks, bb); \
  MM1((mh)*4+3, (nh)*2+0, ks, bb); MM1((mh)*4+3, (nh)*2+1, ks, bb); }
#define MM(mh, nh, bb) { \
  __builtin_amdgcn_s_setprio(1); \
  MMKS(mh, nh, 0, bb); MMKS(mh, nh, 1, bb); \
  __builtin_amdgcn_s_setprio(0); }

#define STGA(buf, q, ku) { \
  gload16(xbp + aoff[0][q] + (ku), &sA[buf][0][(q)*4096 + t8]); \
  gload16(xbp + aoff[1][q] + (ku), &sA[buf][1][(q)*4096 + t8]); }
#define STGB(buf, h, ku) { \
  gload16(wbp + boff[h][0] + (ku), &sB[buf][h][t8]); \
  gload16(wbp + boff[h][1] + (ku), &sB[buf][h][4096 + t8]); }

__global__ __launch_bounds__(512, 2)
void gemm256(const unsigned short* __restrict__ xbp, const unsigned short* __restrict__ wbp,
             const float* __restrict__ bias, float* __restrict__ out) {
  __shared__ unsigned short sA[2][2][8192];
  __shared__ unsigned short sB[2][2][8192];

  // XCD-aware bijective swizzle: grid 512 = 32(M) x 16(N), 512 % 8 == 0
  const int bid = blockIdx.x;
  const int swz = (bid & 7) * 64 + (bid >> 3);
  const int bm = swz >> 4;
  const int bn = swz & 15;

  const int t = threadIdx.x;
  const int lane = t & 63;
  const int wid = t >> 6;
  const int wm = wid >> 2;        // 0..1 (M half)
  const int wn = wid & 3;         // 0..3
  const int wnh = wn >> 1;        // B half
  const int wnq = wn & 1;         // quarter within B half
  const int fr = lane & 15;
  const int ko = (lane >> 4) * 8;
  const int xr = (fr & 7) << 3;   // read-side XOR swizzle
  const int koo0 = ko ^ xr;
  const int koo1 = (32 + ko) ^ xr;

  const int t8 = t * 8;
  const int rl = t >> 3;                          // local row 0..63 (per q)
  const int cs = ((t & 7) * 8) ^ ((rl & 7) << 3); // inverse-swizzled src col
  size_t aoff[2][2], boff[2][2];
#pragma unroll
  for (int h = 0; h < 2; h++)
#pragma unroll
    for (int q = 0; q < 2; q++) {
      aoff[h][q] = (size_t)(bm * 256 + h * 128 + q * 64 + rl) * KDIM + cs;
      boff[h][q] = (size_t)(bn * 256 + h * 128 + q * 64 + rl) * KDIM + cs;
    }

  f32x4 acc[8][4];
#pragma unroll
  for (int i = 0; i < 8; i++)
#pragma unroll
    for (int j = 0; j < 4; j++) acc[i][j] = {0.f, 0.f, 0.f, 0.f};

  bf16x8 a[4][2], b0[2][2], b1[2][2];

  // prologue: T0 full (8 loads) + T1.B0,B1,A0 (6) = 14 outstanding
  STGB(0, 0, 0); STGB(0, 1, 0); STGA(0, 0, 0); STGA(0, 1, 0);
  STGB(1, 0, 64); STGB(1, 1, 64); STGA(1, 0, 64);
  VM6; PSYNC;                      // confirm T0's 8; invariant: 6 outstanding

  const int NIT = KDIM / 128;      // 32 iterations, 2 K-tiles each
  for (int it = 0; it < NIT; ++it) {
    const bool last = (it == NIT - 1);
    const int kuB = it * 128 + 64;   // T1 (buf1) K offset
    const int kuN = kuB + 64;        // T0' (buf0 next)
    const int kuL = kuB + 128;       // T1' (buf1 next)

    // ---- tile T0 (buf0): quadrants (0,0),(0,1),(1,1),(1,0) ----
    LDA(0, 0); LDBX(0, 0, b0);
    STGA(1, 1, kuB);                 // T1.A1 (region dead since prev ph7)
    LGK8; PSYNC;
    MM(0, 0, b0); PSYNC;

    LDBX(0, 1, b1);
    PSYNC;
    MM(0, 1, b1); PSYNC;

    LDA(0, 1);
    if (!last) { STGB(0, 0, kuN); STGB(0, 1, kuN); }  // T0'.B (dead since ph2)
    PSYNC;
    MM(1, 1, b1); PSYNC;

    if (!last) STGA(0, 0, kuN);      // T0'.A0 (dead since ph1)
    if (last) { VM0; } else { VM6; } // confirm T1 (8 oldest of 14)
    PSYNC;
    MM(1, 0, b0); PSYNC;

    // ---- tile T1 (buf1) ----
    LDA(1, 0); LDBX(1, 0, b0);
    if (!last) STGA(0, 1, kuN);      // T0'.A1 (dead since ph3)
    LGK8; PSYNC;
    MM(0, 0, b0); PSYNC;

    LDBX(1, 1, b1);
    PSYNC;
    MM(0, 1, b1); PSYNC;

    LDA(1, 1);
    if (!last) { STGB(1, 0, kuL); STGB(1, 1, kuL); }  // T1'.B (dead since ph6)
    PSYNC;
    MM(1, 1, b1); PSYNC;

    if (!last) { STGA(1, 0, kuL); VM6; }  // T1'.A0; confirm T0' (8 oldest)
    PSYNC;
    MM(1, 0, b0); PSYNC;
  }

  // epilogue: C/D layout col = lane&15, row = (lane>>4)*4 + q
#pragma unroll
  for (int nn = 0; nn < 4; ++nn) {
    const int col = bn * 256 + wn * 64 + nn * 16 + (lane & 15);
    const float bv = bias[col];
#pragma unroll
    for (int m = 0; m < 8; ++m) {
      const int row0 = bm * 256 + wm * 128 + m * 16 + (lane >> 4) * 4;
#pragma unroll
      for (int q = 0; q < 4; ++q)
        out[(size_t)(row0 + q) * NDIM + col] = acc[m][nn][q] + bv;
    }
  }
}

// ===== fallback 128^2 GEMM (round-3 verified) for small-ws paths =====
template <bool A_BF16, bool B_BF16>
__global__ __launch_bounds__(256)
void gemm_bt(const void* __restrict__ Av, const void* __restrict__ Bv,
             const float* __restrict__ bias, float* __restrict__ out,
             const float* __restrict__ scal) {
  __shared__ unsigned short sAt[2][128 * 32];
  __shared__ unsigned short sBt[2][128 * 32];
  float lower = 0.f, upper = 0.f, scale = 0.f;
  if constexpr (!B_BF16) { lower = scal[1]; upper = scal[2]; scale = scal[3]; }
  const unsigned short* Ab = (const unsigned short*)Av;
  const float* Af = (const float*)Av;
  const unsigned short* Bb = (const unsigned short*)Bv;
  const float* Bf = (const float*)Bv;
  int bid = blockIdx.x;
  int swz = (bid & 7) * 256 + (bid >> 3);
  int bm = swz >> 5, bn = swz & 31;
  const int t = threadIdx.x, lane = t & 63, wid = t >> 6;
  const int wm = wid >> 1, wn = wid & 1;
  const int e0 = t * 8, e1 = e0 + 2048;
  const size_t aOff0 = (size_t)(bm * 128 + (e0 >> 5)) * KDIM + (e0 & 31);
  const size_t aOff1 = (size_t)(bm * 128 + (e1 >> 5)) * KDIM + (e1 & 31);
  const size_t bOff0 = (size_t)(bn * 128 + (e0 >> 5)) * KDIM + (e0 & 31);
  const size_t bOff1 = (size_t)(bn * 128 + (e1 >> 5)) * KDIM + (e1 & 31);
  f32x4 acc[4][4];
#pragma unroll
  for (int i = 0; i < 4; i++)
#pragma unroll
    for (int j = 0; j < 4; j++) acc[i][j] = {0.f, 0.f, 0.f, 0.f};
  auto stage = [&](int buf, int k0) {
    if constexpr (A_BF16) {
      gload16(Ab + aOff0 + k0, &sAt[buf][e0]);
      gload16(Ab + aOff1 + k0, &sAt[buf][e1]);
    } else {
      pack8(Af + aOff0 + k0, &sAt[buf][e0], false, 0.f, 0.f, 0.f);
      pack8(Af + aOff1 + k0, &sAt[buf][e1], false, 0.f, 0.f, 0.f);
    }
    if constexpr (B_BF16) {
      gload16(Bb + bOff0 + k0, &sBt[buf][e0]);
      gload16(Bb + bOff1 + k0, &sBt[buf][e1]);
    } else {
      pack8(Bf + bOff0 + k0, &sBt[buf][e0], true, lower, upper, scale);
      pack8(Bf + bOff1 + k0, &sBt[buf][e1], true, lower, upper, scale);
    }
  };
  stage(0, 0);
  const int NT = KDIM / 32;
  const int ko = (lane >> 4) * 8, fr = lane & 15;
  for (int tt = 0; tt < NT; ++tt) {
    int cur = tt & 1;
    __syncthreads();
    if (tt + 1 < NT) stage(cur ^ 1, (tt + 1) * 32);
    bf16x8 a[4], b[4];
#pragma unroll
    for (int i = 0; i < 4; i++) {
      a[i] = *(const bf16x8*)&sAt[cur][(wm * 64 + i * 16 + fr) * 32 + ko];
      b[i] = *(const bf16x8*)&sBt[cur][(wn * 64 + i * 16 + fr) * 32 + ko];
    }
#pragma unroll
    for (int i = 0; i < 4; i++)
#pragma unroll
      for (int j = 0; j < 4; j++)
        acc[i][j] = __builtin_amdgcn_mfma_f32_16x16x32_bf16(a[i], b[j], acc[i][j], 0, 0, 0);
  }
  const int colbase = bn * 128 + wn * 64 + (lane & 15);
  const int rowbase = bm * 128 + wm * 64 + (lane >> 4) * 4;
#pragma unroll
  for (int j = 0; j < 4; j++) {
    int col = colbase + j * 16;
    float bv = bias[col];
#pragma unroll
    for (int i = 0; i < 4; i++) {
      int row0 = rowbase + i * 16;
#pragma unroll
      for (int q = 0; q < 4; q++)
        out[(size_t)(row0 + q) * NDIM + col] = acc[i][j][q] + bv;
    }
  }
}

extern "C" void kernel_launch(void* const* d_in, const int* in_sizes, int n_in,
                              void* d_out, int out_size, void* d_ws, size_t ws_size,
                              hipStream_t stream) {
  const float* x = (const float*)d_in[0];
  const float* w = (const float*)d_in[1];
  const float* bias = (const float*)d_in[2];
  float* out = (float*)d_out;
  char* ws = (char*)d_ws;

  const size_t xb_b = (size_t)XELEMS * 2;   // 64 MB
  const size_t wb_b = (size_t)WELEMS * 2;   // 32 MB
  const size_t c_b = 4 * 4096 * sizeof(float);
  const bool full = ws_size >= xb_b + wb_b + c_b + 64;
  const bool wonly = !full && ws_size >= wb_b + c_b + 64;

  unsigned short *xb = nullptr, *wb = nullptr;
  float *C1, *scal;
  if (full) {
    xb = (unsigned short*)ws;
    wb = (unsigned short*)(ws + xb_b);
    C1 = (float*)(ws + xb_b + wb_b);
  } else if (wonly) {
    wb = (unsigned short*)ws;
    C1 = (float*)(ws + wb_b);
  } else {
    C1 = (float*)ws;
  }
  float* C2 = C1 + 4096;
  float* C3 = C2 + 4096;
  float* C4 = C3 + 4096;
  scal = C4 + 4096;

  np_stage1<0><<<dim3(4096), dim3(256), 0, stream>>>(w, C1, nullptr, scal);
  np_stage2<0><<<dim3(1), dim3(256), 0, stream>>>(C1, nullptr, scal);
  np_stage1<1><<<dim3(4096), dim3(256), 0, stream>>>(w, C2, nullptr, scal);
  np_stage2<1><<<dim3(1), dim3(256), 0, stream>>>(C2, nullptr, scal);
  np_stage1<2><<<dim3(4096), dim3(256), 0, stream>>>(w, C3, C4, scal);
  np_stage2<2><<<dim3(1), dim3(256), 0, stream>>>(C3, C4, scal);

  if (full) {
    convert_w<<<dim3(2048), dim3(256), 0, stream>>>(w, wb, scal);
    convert_x<<<dim3(4096), dim3(256), 0, stream>>>(x, xb);
    gemm256<<<dim3(512), dim3(512), 0, stream>>>(xb, wb, bias, out);
  } else if (wonly) {
    convert_w<<<dim3(2048), dim3(256), 0, stream>>>(w, wb, scal);
    gemm_bt<false, true><<<dim3(2048), dim3(256), 0, stream>>>(x, wb, bias, out, scal);
  } else {
    gemm_bt<false, false><<<dim3(2048), dim3(256), 0, stream>>>(x, w, bias, out, scal);
  }
}